// Round 19
// baseline (418.393 us; speedup 1.0000x reference)
//
#include <hip/hip_runtime.h>
#include <cstdint>

typedef unsigned short u16;
typedef float  f32x4 __attribute__((ext_vector_type(4)));
typedef short  s16x4 __attribute__((ext_vector_type(4)));
typedef short  s16x8 __attribute__((ext_vector_type(8)));

#define D_IN  4096
#define D_OUT 4096
#define RMOE  128
#define KAUG  4224   /* D_IN + RMOE */
#define NTOK  8192   /* B*S = 4*2048 */

__device__ __forceinline__ u16 f2bf(float f) {
    unsigned u = __builtin_bit_cast(unsigned, f);
    unsigned r = u + 0x7fffu + ((u >> 16) & 1u);   // RNE
    return (u16)(r >> 16);
}

__device__ __forceinline__ void gload16(const void* g, void* l) {
    __builtin_amdgcn_global_load_lds(
        (const __attribute__((address_space(1))) void*)g,
        (__attribute__((address_space(3))) void*)l, 16, 0, 0);
}

// ---------------------------------------------------------------------------
// Kernel 1 (HORIZONTAL FUSION, validated R18): blocks 0..2047 router+x-conv;
// blocks 2048..10751 bw/lora_B/lora_A conversions.
// ---------------------------------------------------------------------------
__global__ __launch_bounds__(256)
void prep_kernel(const float* __restrict__ x, const float* __restrict__ rw,
                 const float* __restrict__ scal, const float* __restrict__ bw,
                 const float* __restrict__ lA, const float* __restrict__ lB,
                 u16* __restrict__ Xaug, u16* __restrict__ Waug,
                 u16* __restrict__ A16, float* __restrict__ gates) {
    if (blockIdx.x < 2048) {
        int wave = threadIdx.x >> 6, lane = threadIdx.x & 63;
        int t = blockIdx.x * 4 + wave;
        const float4* xp = (const float4*)(x + (long)t * D_IN);
        u16* xa = Xaug + (long)t * KAUG;
        float acc[8];
#pragma unroll
        for (int e = 0; e < 8; ++e) acc[e] = 0.f;
#pragma unroll 4
        for (int i = 0; i < 16; ++i) {
            float4 xv = xp[i * 64 + lane];
            s16x4 o;
            o[0] = (short)f2bf(xv.x); o[1] = (short)f2bf(xv.y);
            o[2] = (short)f2bf(xv.z); o[3] = (short)f2bf(xv.w);
            *(s16x4*)(xa + (i * 64 + lane) * 4) = o;
#pragma unroll
            for (int e = 0; e < 8; ++e) {
                float4 wv = ((const float4*)(rw + (long)e * D_IN))[i * 64 + lane];
                acc[e] += xv.x * wv.x + xv.y * wv.y + xv.z * wv.z + xv.w * wv.w;
            }
        }
#pragma unroll
        for (int e = 0; e < 8; ++e) {
#pragma unroll
            for (int off = 32; off > 0; off >>= 1)
                acc[e] += __shfl_xor(acc[e], off, 64);
        }
        if (lane == 0) {
            int i1 = 0; float v1 = acc[0];
#pragma unroll
            for (int e = 1; e < 8; ++e) if (acc[e] > v1) { v1 = acc[e]; i1 = e; }
            int i2 = -1; float v2 = -3.4e38f;
#pragma unroll
            for (int e = 0; e < 8; ++e) if (e != i1 && acc[e] > v2) { v2 = acc[e]; i2 = e; }
            float g1 = 1.f / (1.f + expf(v2 - v1));
            float g2 = 1.f - g1;
            float* gp = gates + (long)t * 8;
#pragma unroll
            for (int e = 0; e < 8; ++e)
                gp[e] = (e == i1) ? g1 * scal[e] : ((e == i2) ? g2 * scal[e] : 0.f);
        }
    } else {
        const long nw = (long)D_OUT * D_IN / 8;   // 2,097,152
        const long nb = (long)D_OUT * RMOE / 8;   // 65,536
        long tid = (long)(blockIdx.x - 2048) * 256 + threadIdx.x;
        const float* src; u16* dst;
        if (tid < nw) {
            long e = tid * 8; long row = e >> 12; long col = e & 4095;
            src = bw + e; dst = Waug + row * KAUG + col;
        } else if (tid < nw + nb) {
            long e = (tid - nw) * 8; long row = e >> 7; long col = e & 127;
            src = lB + e; dst = Waug + row * KAUG + D_IN + col;
        } else {
            long e = (tid - nw - nb) * 8;
            src = lA + e; dst = A16 + e;
        }
        float4 a = ((const float4*)src)[0];
        float4 b = ((const float4*)src)[1];
        s16x8 o;
        o[0] = (short)f2bf(a.x); o[1] = (short)f2bf(a.y);
        o[2] = (short)f2bf(a.z); o[3] = (short)f2bf(a.w);
        o[4] = (short)f2bf(b.x); o[5] = (short)f2bf(b.y);
        o[6] = (short)f2bf(b.z); o[7] = (short)f2bf(b.w);
        *(s16x8*)dst = o;
    }
}

// ---------------------------------------------------------------------------
// Kernel 2 (validated R18): lora_h BM=64, BN=32, grid 512.
// ---------------------------------------------------------------------------
__global__ __launch_bounds__(256)
void lora_h_kernel(u16* __restrict__ Xaug, const u16* __restrict__ A16,
                   const float* __restrict__ gates) {
    __shared__ u16 sX[64 * 32];
    __shared__ u16 sW[32 * 32];
    int tid = threadIdx.x, wave = tid >> 6, lane = tid & 63;
    int bm = blockIdx.x >> 2, bn = blockIdx.x & 3;     // 128 x 4
    long m0 = (long)bm * 64; int n0 = bn * 32;
    int wr = wave >> 1, wc = wave & 1;
    int rowA = tid >> 2, oct = tid & 3;
    const u16* gx = Xaug + (m0 + rowA) * KAUG + oct * 8;
    const u16* gw = A16 + (long)(n0 + rowA) * D_IN + oct * 8;  // used only rowA<32
    u16* lx = sX + wave * 512;
    u16* lw = sW + wave * 512;   // only waves 0,1 stage B
    int cl = lane & 15, kh = lane >> 4;
    int aoff[2];
#pragma unroll
    for (int i = 0; i < 2; ++i)
        aoff[i] = (wr * 32 + i * 16 + cl) * 32 + kh * 8;
    int boff = (wc * 16 + cl) * 32 + kh * 8;
    f32x4 acc2[2];
    acc2[0] = (f32x4){0.f, 0.f, 0.f, 0.f};
    acc2[1] = (f32x4){0.f, 0.f, 0.f, 0.f};
    for (int kt = 0; kt < 128; ++kt) {
        __syncthreads();
        gload16(gx, lx);
        if (tid < 128) gload16(gw, lw);
        gx += 32; gw += 32;
        __syncthreads();
        s16x8 a[2], b;
        a[0] = *(const s16x8*)&sX[aoff[0]];
        a[1] = *(const s16x8*)&sX[aoff[1]];
        b = *(const s16x8*)&sW[boff];
#pragma unroll
        for (int mi = 0; mi < 2; ++mi)
            acc2[mi] = __builtin_amdgcn_mfma_f32_16x16x32_bf16(
                a[mi], b, acc2[mi], 0, 0, 0);
    }
    int col = n0 + wc * 16 + cl;     // rank 0..127
    int g = col >> 4;
#pragma unroll
    for (int mi = 0; mi < 2; ++mi) {
#pragma unroll
        for (int r = 0; r < 4; ++r) {
            long tok = m0 + wr * 32 + mi * 16 + kh * 4 + r;
            float v = acc2[mi][r] * gates[tok * 8 + g];
            Xaug[tok * KAUG + D_IN + col] = f2bf(v);
        }
    }
}

// ---------------------------------------------------------------------------
// Kernel 3 (ROUND-19): main GEMM re-geometried for 2 BLOCKS/CU.
// Tile 256x128, BK=32, 8 waves (4M x 2N) of 64x64 (acc 4x4 = 64 regs,
// 8 ds_reads + 16 MFMA per wave per K-step). LDS: 2 buffers x 24 KB = 48 KB.
// __launch_bounds__(512,4) caps total regs at 128 -> 16 waves/CU.
// Mechanism (m114): two co-resident blocks run anti-phased; one block's
// barrier/drain stalls are covered by the other's MFMA -> LDS || MFMA
// overlap that single-block schedules (R13-R15) could never reach.
//
// Sync = validated R5 ordering: vmcnt(0) BEFORE barrier (each wave proves
// its stage landed, then all sync); STAGE(t+1) -> buf[(t+1)&1], whose
// readers (tile t-1) lgkm-drained before barrier(t). T1 bijective swizzle
// (1024 % 8 == 0), T2 slot-XOR swizzle (same algebra: row ≡ cl mod 16).
// ---------------------------------------------------------------------------
__global__ __launch_bounds__(512, 4)
void main_gemm(const u16* __restrict__ Xaug, const u16* __restrict__ Waug,
               const float* __restrict__ bias, float* __restrict__ out) {
    __shared__ u16 lds[2 * 12288];     // 48 KiB
    const int tid = threadIdx.x;
    const int wave = tid >> 6, lane = tid & 63;
    const int cl = lane & 15, kh = lane >> 4;
    const int wr = wave >> 1, wc = wave & 1;

    // T1: bijective XCD swizzle (1024 blocks, 1024 % 8 == 0)
    int bid = blockIdx.x;
    int swz = (bid & 7) * 128 + (bid >> 3);
    long m0 = (long)(swz & 31) * 256;   // 32 M-blocks
    long n0 = (long)(swz >> 5) * 128;   // 32 N-blocks

    // staging: thread covers row (tid>>2) [+128 for A's 2nd half], slot tid&3;
    // T2 source slot XOR'd by ((row>>1)&3) == ((tid>>3)&3).
    const int rA = tid >> 2;
    const int sl = (((tid & 3) ^ ((tid >> 3) & 3))) * 8;
    const u16* gA0 = Xaug + (m0 + rA) * KAUG + sl;
    const u16* gA1 = Xaug + (m0 + 128 + rA) * KAUG + sl;
    const u16* gB0 = Waug + (n0 + rA) * KAUG + sl;   // rA < 128 rows used
    const int wbase = wave * 512;       // wave-uniform LDS base (el)

    // T2 read side: slot kh ^ ((row>>1)&3); row ≡ cl (mod 16) in all frags.
    const int swk = (kh ^ ((cl >> 1) & 3)) * 8;
    const int aob = (wr * 64 + cl) * 32 + swk;             // + m*512
    const int bob = 8192 + (wc * 64 + cl) * 32 + swk;      // + n*512

    f32x4 acc[4][4];
#pragma unroll
    for (int m = 0; m < 4; ++m)
#pragma unroll
        for (int n = 0; n < 4; ++n) acc[m][n] = (f32x4){0.f, 0.f, 0.f, 0.f};

#define STAGE(t) do { u16* L = lds + ((t) & 1) * 12288 + wbase;              \
        gload16(gA0 + (t) * 32, L);                                          \
        gload16(gA1 + (t) * 32, L + 4096);                                   \
        gload16(gB0 + (t) * 32, L + 8192); } while (0)

    s16x8 av[4], bv[4];

    STAGE(0);

    for (int t = 0; t < 132; ++t) {
        asm volatile("s_waitcnt vmcnt(0)" ::: "memory");   // st(t) landed
        __builtin_amdgcn_s_barrier();
        __builtin_amdgcn_sched_barrier(0);
        if (t + 1 < 132) STAGE(t + 1);                     // into freed buffer
        const u16* Lb = lds + (t & 1) * 12288;
#pragma unroll
        for (int m = 0; m < 4; ++m) av[m] = *(const s16x8*)&Lb[aob + m * 512];
#pragma unroll
        for (int n = 0; n < 4; ++n) bv[n] = *(const s16x8*)&Lb[bob + n * 512];
        asm volatile("s_waitcnt lgkmcnt(0)" ::: "memory");
        __builtin_amdgcn_sched_barrier(0);
        __builtin_amdgcn_s_setprio(1);
#pragma unroll
        for (int m = 0; m < 4; ++m)
#pragma unroll
            for (int n = 0; n < 4; ++n)
                acc[m][n] = __builtin_amdgcn_mfma_f32_16x16x32_bf16(
                    av[m], bv[n], acc[m][n], 0, 0, 0);
        __builtin_amdgcn_s_setprio(0);
    }
#undef STAGE

#pragma unroll
    for (int n = 0; n < 4; ++n) {
        long col = n0 + wc * 64 + n * 16 + cl;
        float bvv = bias[col];
#pragma unroll
        for (int m = 0; m < 4; ++m) {
            long row = m0 + wr * 64 + m * 16 + kh * 4;
#pragma unroll
            for (int r = 0; r < 4; ++r)
                out[(row + r) * (long)D_OUT + col] = acc[m][n][r] + bvv;
        }
    }
}

// ---------------------------------------------------------------------------
extern "C" void kernel_launch(void* const* d_in, const int* in_sizes, int n_in,
                              void* d_out, int out_size, void* d_ws, size_t ws_size,
                              hipStream_t stream) {
    const float* x  = (const float*)d_in[0];
    const float* bw = (const float*)d_in[1];
    const float* bb = (const float*)d_in[2];
    const float* lA = (const float*)d_in[3];
    const float* lB = (const float*)d_in[4];
    const float* rw = (const float*)d_in[5];
    const float* sc = (const float*)d_in[6];
    float* out = (float*)d_out;

    char* ws = (char*)d_ws;
    u16* Xaug  = (u16*)ws;                      // 8192*4224*2 = 69,206,016 B
    u16* Waug  = (u16*)(ws + 69206016);         // 4096*4224*2 = 34,603,008 B
    u16* A16   = (u16*)(ws + 103809024);        // 128*4096*2  =  1,048,576 B
    float* gates = (float*)(ws + 104857600);    // 8192*8*4    =    262,144 B

    prep_kernel<<<10752, 256, 0, stream>>>(x, rw, sc, bw, lA, lB,
                                           Xaug, Waug, A16, gates);
    lora_h_kernel<<<512, 256, 0, stream>>>(Xaug, A16, gates);
    main_gemm<<<1024, 512, 0, stream>>>(Xaug, Waug, bb, out);
}

// Round 20
// 380.115 us; speedup vs baseline: 1.1007x; 1.1007x over previous
//
#include <hip/hip_runtime.h>
#include <cstdint>

typedef unsigned short u16;
typedef float  f32x4 __attribute__((ext_vector_type(4)));
typedef short  s16x4 __attribute__((ext_vector_type(4)));
typedef short  s16x8 __attribute__((ext_vector_type(8)));

#define D_IN  4096
#define D_OUT 4096
#define RMOE  128
#define KAUG  4224   /* D_IN + RMOE = 66 * 64 */
#define NTOK  8192   /* B*S = 4*2048 */

__device__ __forceinline__ u16 f2bf(float f) {
    unsigned u = __builtin_bit_cast(unsigned, f);
    unsigned r = u + 0x7fffu + ((u >> 16) & 1u);   // RNE
    return (u16)(r >> 16);
}

__device__ __forceinline__ void gload16(const void* g, void* l) {
    __builtin_amdgcn_global_load_lds(
        (const __attribute__((address_space(1))) void*)g,
        (__attribute__((address_space(3))) void*)l, 16, 0, 0);
}

// ---------------------------------------------------------------------------
// Kernel 1 (HORIZONTAL FUSION, validated R18): blocks 0..2047 router+x-conv;
// blocks 2048..10751 bw/lora_B/lora_A conversions.
// ---------------------------------------------------------------------------
__global__ __launch_bounds__(256)
void prep_kernel(const float* __restrict__ x, const float* __restrict__ rw,
                 const float* __restrict__ scal, const float* __restrict__ bw,
                 const float* __restrict__ lA, const float* __restrict__ lB,
                 u16* __restrict__ Xaug, u16* __restrict__ Waug,
                 u16* __restrict__ A16, float* __restrict__ gates) {
    if (blockIdx.x < 2048) {
        int wave = threadIdx.x >> 6, lane = threadIdx.x & 63;
        int t = blockIdx.x * 4 + wave;
        const float4* xp = (const float4*)(x + (long)t * D_IN);
        u16* xa = Xaug + (long)t * KAUG;
        float acc[8];
#pragma unroll
        for (int e = 0; e < 8; ++e) acc[e] = 0.f;
#pragma unroll 4
        for (int i = 0; i < 16; ++i) {
            float4 xv = xp[i * 64 + lane];
            s16x4 o;
            o[0] = (short)f2bf(xv.x); o[1] = (short)f2bf(xv.y);
            o[2] = (short)f2bf(xv.z); o[3] = (short)f2bf(xv.w);
            *(s16x4*)(xa + (i * 64 + lane) * 4) = o;
#pragma unroll
            for (int e = 0; e < 8; ++e) {
                float4 wv = ((const float4*)(rw + (long)e * D_IN))[i * 64 + lane];
                acc[e] += xv.x * wv.x + xv.y * wv.y + xv.z * wv.z + xv.w * wv.w;
            }
        }
#pragma unroll
        for (int e = 0; e < 8; ++e) {
#pragma unroll
            for (int off = 32; off > 0; off >>= 1)
                acc[e] += __shfl_xor(acc[e], off, 64);
        }
        if (lane == 0) {
            int i1 = 0; float v1 = acc[0];
#pragma unroll
            for (int e = 1; e < 8; ++e) if (acc[e] > v1) { v1 = acc[e]; i1 = e; }
            int i2 = -1; float v2 = -3.4e38f;
#pragma unroll
            for (int e = 0; e < 8; ++e) if (e != i1 && acc[e] > v2) { v2 = acc[e]; i2 = e; }
            float g1 = 1.f / (1.f + expf(v2 - v1));
            float g2 = 1.f - g1;
            float* gp = gates + (long)t * 8;
#pragma unroll
            for (int e = 0; e < 8; ++e)
                gp[e] = (e == i1) ? g1 * scal[e] : ((e == i2) ? g2 * scal[e] : 0.f);
        }
    } else {
        const long nw = (long)D_OUT * D_IN / 8;   // 2,097,152
        const long nb = (long)D_OUT * RMOE / 8;   // 65,536
        long tid = (long)(blockIdx.x - 2048) * 256 + threadIdx.x;
        const float* src; u16* dst;
        if (tid < nw) {
            long e = tid * 8; long row = e >> 12; long col = e & 4095;
            src = bw + e; dst = Waug + row * KAUG + col;
        } else if (tid < nw + nb) {
            long e = (tid - nw) * 8; long row = e >> 7; long col = e & 127;
            src = lB + e; dst = Waug + row * KAUG + D_IN + col;
        } else {
            long e = (tid - nw - nb) * 8;
            src = lA + e; dst = A16 + e;
        }
        float4 a = ((const float4*)src)[0];
        float4 b = ((const float4*)src)[1];
        s16x8 o;
        o[0] = (short)f2bf(a.x); o[1] = (short)f2bf(a.y);
        o[2] = (short)f2bf(a.z); o[3] = (short)f2bf(a.w);
        o[4] = (short)f2bf(b.x); o[5] = (short)f2bf(b.y);
        o[6] = (short)f2bf(b.z); o[7] = (short)f2bf(b.w);
        *(s16x8*)dst = o;
    }
}

// ---------------------------------------------------------------------------
// Kernel 2 (validated R18): lora_h BM=64, BN=32, grid 512.
// ---------------------------------------------------------------------------
__global__ __launch_bounds__(256)
void lora_h_kernel(u16* __restrict__ Xaug, const u16* __restrict__ A16,
                   const float* __restrict__ gates) {
    __shared__ u16 sX[64 * 32];
    __shared__ u16 sW[32 * 32];
    int tid = threadIdx.x, wave = tid >> 6, lane = tid & 63;
    int bm = blockIdx.x >> 2, bn = blockIdx.x & 3;     // 128 x 4
    long m0 = (long)bm * 64; int n0 = bn * 32;
    int wr = wave >> 1, wc = wave & 1;
    int rowA = tid >> 2, oct = tid & 3;
    const u16* gx = Xaug + (m0 + rowA) * KAUG + oct * 8;
    const u16* gw = A16 + (long)(n0 + rowA) * D_IN + oct * 8;  // used only rowA<32
    u16* lx = sX + wave * 512;
    u16* lw = sW + wave * 512;   // only waves 0,1 stage B
    int cl = lane & 15, kh = lane >> 4;
    int aoff[2];
#pragma unroll
    for (int i = 0; i < 2; ++i)
        aoff[i] = (wr * 32 + i * 16 + cl) * 32 + kh * 8;
    int boff = (wc * 16 + cl) * 32 + kh * 8;
    f32x4 acc2[2];
    acc2[0] = (f32x4){0.f, 0.f, 0.f, 0.f};
    acc2[1] = (f32x4){0.f, 0.f, 0.f, 0.f};
    for (int kt = 0; kt < 128; ++kt) {
        __syncthreads();
        gload16(gx, lx);
        if (tid < 128) gload16(gw, lw);
        gx += 32; gw += 32;
        __syncthreads();
        s16x8 a[2], b;
        a[0] = *(const s16x8*)&sX[aoff[0]];
        a[1] = *(const s16x8*)&sX[aoff[1]];
        b = *(const s16x8*)&sW[boff];
#pragma unroll
        for (int mi = 0; mi < 2; ++mi)
            acc2[mi] = __builtin_amdgcn_mfma_f32_16x16x32_bf16(
                a[mi], b, acc2[mi], 0, 0, 0);
    }
    int col = n0 + wc * 16 + cl;     // rank 0..127
    int g = col >> 4;
#pragma unroll
    for (int mi = 0; mi < 2; ++mi) {
#pragma unroll
        for (int r = 0; r < 4; ++r) {
            long tok = m0 + wr * 32 + mi * 16 + kh * 4 + r;
            float v = acc2[mi][r] * gates[tok * 8 + g];
            Xaug[tok * KAUG + D_IN + col] = f2bf(v);
        }
    }
}

// ---------------------------------------------------------------------------
// Kernel 3 (ROUND-20): m201 8-phase template port. 256x256 tile, BK=64,
// 8 waves (2M x 4N, wave tile 128x64), 66 K-tiles = 33 iters of 2.
// LDS 128KB: A[2buf][2half][128][64] + B[same] bf16.
// Per phase: {ds_reads (4 A-frag; +8 B at p0/p4), 1 half-tile stage,
// barrier, lgkm0+sched_barrier, setprio 16 MFMA, [vmcnt(4) at p3/p7],
// barrier}. Counted vmcnt never drains to 0 in steady state (T4).
//
// Stage stream (FIFO) per iter i (k0=2i,k1=2i+1,k2=2i+2,k3=2i+3):
//   p0:A-h0(k1) p1:A-h1(k1) p2:B-h0(k2) p3:B-h1(k2)
//   p4:A-h0(k2) p5:A-h1(k2) p6:B-h0(k3) p7:B-h1(k3)
// Safety: each stage's target region last-read >=1 phase earlier (all
// waves' reads lgkm0-drained before their MFMA + barrier). Gates:
//   p3: needs A(k1)[p0,p1]+B(k1)[i-1 p6,p7]; newer = p2,p3 = 4 -> vmcnt(4)
//   p7: needs A(k2)[p4,p5]+B(k2)[p2,p3]; newer = p6,p7 = 4 -> vmcnt(4)
// Tail i=32: stages of k2,k3 skipped; p3 gate -> vmcnt(0).
// Swizzle (both-sides involution): read slot (kk*4+kh)^(cl&7); staging
// source slot (tid&7)^((tid>>3)&7); rows 128B => <=2-way banks.
// ---------------------------------------------------------------------------
__global__ __launch_bounds__(512, 2)
void main_gemm(const u16* __restrict__ Xaug, const u16* __restrict__ Waug,
               const float* __restrict__ bias, float* __restrict__ out) {
    __shared__ u16 lds[65536];     // 128 KiB
    const int tid = threadIdx.x;
    const int wave = tid >> 6, lane = tid & 63;
    const int cl = lane & 15, kh = lane >> 4;
    const int wr = wave >> 2, wc = wave & 3;

    // T1: bijective XCD swizzle (512 blocks, 512 % 8 == 0)
    int bid = blockIdx.x;
    int swz = (bid & 7) * 64 + (bid >> 3);
    long m0 = (long)(swz & 31) * 256;   // 32 M-blocks
    long n0 = (long)(swz >> 5) * 256;   // 16 N-blocks

    // staging: thread -> row rbase (0..63 within 64-row chunk), slot sstg
    const int rbase = tid >> 3;
    const int sstg = ((tid & 7) ^ ((tid >> 3) & 7)) * 8;   // el offset
    const u16* gA = Xaug + (m0 + rbase) * KAUG + sstg;
    const u16* gB = Waug + (n0 + rbase) * KAUG + sstg;
    const int wst = (tid >> 6) * 512;   // wave-uniform LDS base (el)

    // read offsets (el): A = buf*16384 + wr*8192 + m*1024 + cl*64 + sk
    //                    B = 32768 + buf*16384 + wc*4096 + n*1024 + cl*64 + sk
    const int sk0 = ((kh) ^ (cl & 7)) * 8;
    const int sk1 = ((4 + kh) ^ (cl & 7)) * 8;
    const int ab0 = wr * 8192 + cl * 64;
    const int bb0 = 32768 + wc * 4096 + cl * 64;

    f32x4 acc[8][4];
#pragma unroll
    for (int m = 0; m < 8; ++m)
#pragma unroll
        for (int n = 0; n < 4; ++n) acc[m][n] = (f32x4){0.f, 0.f, 0.f, 0.f};

    s16x8 av[2][2], bv[4][2];

#define STAGE_A(kt, ht) do {                                                 \
        const u16* g_ = gA + ((long)(ht) * 128) * KAUG + (kt) * 64;          \
        u16* d_ = lds + ((kt) & 1) * 16384 + (ht) * 8192 + wst;              \
        gload16(g_, d_);                                                     \
        gload16(g_ + (long)64 * KAUG, d_ + 4096); } while (0)
#define STAGE_B(kt, ht) do {                                                 \
        const u16* g_ = gB + ((long)(ht) * 128) * KAUG + (kt) * 64;          \
        u16* d_ = lds + 32768 + ((kt) & 1) * 16384 + (ht) * 8192 + wst;      \
        gload16(g_, d_);                                                     \
        gload16(g_ + (long)64 * KAUG, d_ + 4096); } while (0)
#define RD_B(BUFO) do {                                                      \
        const u16* Lb_ = lds + (BUFO) + bb0;                                 \
        _Pragma("unroll")                                                    \
        for (int n_ = 0; n_ < 4; ++n_) {                                     \
            bv[n_][0] = *(const s16x8*)&Lb_[n_ * 1024 + sk0];                \
            bv[n_][1] = *(const s16x8*)&Lb_[n_ * 1024 + sk1]; } } while (0)
#define RD_A2(Q, BUFO) do {                                                  \
        const u16* La_ = lds + (BUFO) + ab0 + (Q) * 2048;                    \
        av[0][0] = *(const s16x8*)&La_[sk0];                                 \
        av[0][1] = *(const s16x8*)&La_[sk1];                                 \
        av[1][0] = *(const s16x8*)&La_[1024 + sk0];                          \
        av[1][1] = *(const s16x8*)&La_[1024 + sk1]; } while (0)
#define MF(Q) do { __builtin_amdgcn_s_setprio(1);                            \
        _Pragma("unroll")                                                    \
        for (int j_ = 0; j_ < 2; ++j_)                                       \
        _Pragma("unroll")                                                    \
        for (int n_ = 0; n_ < 4; ++n_)                                       \
        _Pragma("unroll")                                                    \
        for (int kk_ = 0; kk_ < 2; ++kk_)                                    \
            acc[2 * (Q) + j_][n_] = __builtin_amdgcn_mfma_f32_16x16x32_bf16( \
                av[j_][kk_], bv[n_][kk_], acc[2 * (Q) + j_][n_], 0, 0, 0);   \
        __builtin_amdgcn_s_setprio(0); } while (0)
#define BAR1_LG() do { __builtin_amdgcn_s_barrier();                         \
        asm volatile("s_waitcnt lgkmcnt(0)" ::: "memory");                   \
        __builtin_amdgcn_sched_barrier(0); } while (0)
#define BAR2() do { __builtin_amdgcn_s_barrier();                            \
        __builtin_amdgcn_sched_barrier(0); } while (0)

    // prologue: A(0) h0,h1; B(0) h0,h1; B(1) h0,h1  (12 loads)
    STAGE_A(0, 0); STAGE_A(0, 1);
    STAGE_B(0, 0); STAGE_B(0, 1);
    STAGE_B(1, 0); STAGE_B(1, 1);
    asm volatile("s_waitcnt vmcnt(4)" ::: "memory");   // A(0),B(0) landed
    BAR2();

    for (int i = 0; i < 33; ++i) {
        const int k1 = 2 * i + 1, k2 = 2 * i + 2, k3 = 2 * i + 3;
        const bool ok = (i < 32);
        // ---- K-tile k0 (buf 0) ----
        RD_B(0); RD_A2(0, 0); STAGE_A(k1, 0);
        BAR1_LG(); MF(0); BAR2();
        RD_A2(1, 0); STAGE_A(k1, 1);
        BAR1_LG(); MF(1); BAR2();
        RD_A2(2, 0); if (ok) STAGE_B(k2, 0);
        BAR1_LG(); MF(2); BAR2();
        RD_A2(3, 0); if (ok) STAGE_B(k2, 1);
        BAR1_LG(); MF(3);
        if (ok) asm volatile("s_waitcnt vmcnt(4)" ::: "memory");
        else    asm volatile("s_waitcnt vmcnt(0)" ::: "memory");
        BAR2();
        // ---- K-tile k1 (buf 1) ----
        RD_B(16384); RD_A2(0, 16384); if (ok) STAGE_A(k2, 0);
        BAR1_LG(); MF(0); BAR2();
        RD_A2(1, 16384); if (ok) STAGE_A(k2, 1);
        BAR1_LG(); MF(1); BAR2();
        RD_A2(2, 16384); if (ok) STAGE_B(k3, 0);
        BAR1_LG(); MF(2); BAR2();
        RD_A2(3, 16384); if (ok) STAGE_B(k3, 1);
        BAR1_LG(); MF(3);
        if (ok) asm volatile("s_waitcnt vmcnt(4)" ::: "memory");
        BAR2();
    }
#undef STAGE_A
#undef STAGE_B
#undef RD_B
#undef RD_A2
#undef MF
#undef BAR1_LG
#undef BAR2

#pragma unroll
    for (int n = 0; n < 4; ++n) {
        long col = n0 + wc * 64 + n * 16 + cl;
        float bvv = bias[col];
#pragma unroll
        for (int m = 0; m < 8; ++m) {
            long row = m0 + wr * 128 + m * 16 + kh * 4;
#pragma unroll
            for (int r = 0; r < 4; ++r)
                out[(row + r) * (long)D_OUT + col] = acc[m][n][r] + bvv;
        }
    }
}

// ---------------------------------------------------------------------------
extern "C" void kernel_launch(void* const* d_in, const int* in_sizes, int n_in,
                              void* d_out, int out_size, void* d_ws, size_t ws_size,
                              hipStream_t stream) {
    const float* x  = (const float*)d_in[0];
    const float* bw = (const float*)d_in[1];
    const float* bb = (const float*)d_in[2];
    const float* lA = (const float*)d_in[3];
    const float* lB = (const float*)d_in[4];
    const float* rw = (const float*)d_in[5];
    const float* sc = (const float*)d_in[6];
    float* out = (float*)d_out;

    char* ws = (char*)d_ws;
    u16* Xaug  = (u16*)ws;                      // 8192*4224*2 = 69,206,016 B
    u16* Waug  = (u16*)(ws + 69206016);         // 4096*4224*2 = 34,603,008 B
    u16* A16   = (u16*)(ws + 103809024);        // 128*4096*2  =  1,048,576 B
    float* gates = (float*)(ws + 104857600);    // 8192*8*4    =    262,144 B

    prep_kernel<<<10752, 256, 0, stream>>>(x, rw, sc, bw, lA, lB,
                                           Xaug, Waug, A16, gates);
    lora_h_kernel<<<512, 256, 0, stream>>>(Xaug, A16, gates);
    main_gemm<<<512, 512, 0, stream>>>(Xaug, Waug, bb, out);
}

// Round 21
// 363.162 us; speedup vs baseline: 1.1521x; 1.0467x over previous
//
#include <hip/hip_runtime.h>
#include <cstdint>

typedef unsigned short u16;
typedef float  f32x4 __attribute__((ext_vector_type(4)));
typedef short  s16x4 __attribute__((ext_vector_type(4)));
typedef short  s16x8 __attribute__((ext_vector_type(8)));

#define D_IN  4096
#define D_OUT 4096
#define RMOE  128
#define KAUG  4224   /* D_IN + RMOE = 66 * 64 */
#define NTOK  8192   /* B*S = 4*2048 */

__device__ __forceinline__ u16 f2bf(float f) {
    unsigned u = __builtin_bit_cast(unsigned, f);
    unsigned r = u + 0x7fffu + ((u >> 16) & 1u);   // RNE
    return (u16)(r >> 16);
}

__device__ __forceinline__ void gload16(const void* g, void* l) {
    __builtin_amdgcn_global_load_lds(
        (const __attribute__((address_space(1))) void*)g,
        (__attribute__((address_space(3))) void*)l, 16, 0, 0);
}

// ---------------------------------------------------------------------------
// Kernel 1 (ROUND-21): fused prep. Blocks 0..2047 router+x-conv with rw
// LDS-SHARED across the block's 4 waves (rw L2 traffic /4: each 8KB chunk
// staged once per block via gload16 — per-lane global src, linear
// wave-uniform LDS dst — double-buffered, one __syncthreads per iter whose
// vmcnt/lgkm drain covers the stage). Lane values BIT-IDENTICAL to the
// validated router (same float4s, same accumulation order) -> top-k exact.
// Blocks 2048..10751: bw/lora_B/lora_A conversions (validated R10 logic).
// ---------------------------------------------------------------------------
__global__ __launch_bounds__(256)
void prep_kernel(const float* __restrict__ x, const float* __restrict__ rw,
                 const float* __restrict__ scal, const float* __restrict__ bw,
                 const float* __restrict__ lA, const float* __restrict__ lB,
                 u16* __restrict__ Xaug, u16* __restrict__ Waug,
                 u16* __restrict__ A16, float* __restrict__ gates) {
    __shared__ u16 srw[2][4096];   // 2 x 8KB: [e 0..7][lane 0..63] float4
    if (blockIdx.x < 2048) {
        int wave = threadIdx.x >> 6, lane = threadIdx.x & 63;
        int t = blockIdx.x * 4 + wave;
        const float4* xp = (const float4*)(x + (long)t * D_IN);
        u16* xa = Xaug + (long)t * KAUG;
        float acc[8];
#pragma unroll
        for (int e = 0; e < 8; ++e) acc[e] = 0.f;

        // stage chunk 0: wave w loads expert rows w and w+4
        gload16(rw + wave * 4096 + lane * 4, &srw[0][wave * 512]);
        gload16(rw + (4 + wave) * 4096 + lane * 4, &srw[0][2048 + wave * 512]);

        for (int i = 0; i < 16; ++i) {
            __syncthreads();   // stage(i) landed (vmcnt0), use(i-1) done
            if (i < 15) {
                const float* s = rw + i * 256 + 256;   // chunk i+1
                gload16(s + wave * 4096 + lane * 4,
                        &srw[(i + 1) & 1][wave * 512]);
                gload16(s + (4 + wave) * 4096 + lane * 4,
                        &srw[(i + 1) & 1][2048 + wave * 512]);
            }
            float4 xv = xp[i * 64 + lane];
            s16x4 o;
            o[0] = (short)f2bf(xv.x); o[1] = (short)f2bf(xv.y);
            o[2] = (short)f2bf(xv.z); o[3] = (short)f2bf(xv.w);
            *(s16x4*)(xa + (i * 64 + lane) * 4) = o;
            const float4* wvp = (const float4*)srw[i & 1];
#pragma unroll
            for (int e = 0; e < 8; ++e) {
                float4 wv = wvp[e * 64 + lane];
                acc[e] += xv.x * wv.x + xv.y * wv.y + xv.z * wv.z + xv.w * wv.w;
            }
        }
#pragma unroll
        for (int e = 0; e < 8; ++e) {
#pragma unroll
            for (int off = 32; off > 0; off >>= 1)
                acc[e] += __shfl_xor(acc[e], off, 64);
        }
        if (lane == 0) {
            int i1 = 0; float v1 = acc[0];
#pragma unroll
            for (int e = 1; e < 8; ++e) if (acc[e] > v1) { v1 = acc[e]; i1 = e; }
            int i2 = -1; float v2 = -3.4e38f;
#pragma unroll
            for (int e = 0; e < 8; ++e) if (e != i1 && acc[e] > v2) { v2 = acc[e]; i2 = e; }
            float g1 = 1.f / (1.f + expf(v2 - v1));
            float g2 = 1.f - g1;
            float* gp = gates + (long)t * 8;
#pragma unroll
            for (int e = 0; e < 8; ++e)
                gp[e] = (e == i1) ? g1 * scal[e] : ((e == i2) ? g2 * scal[e] : 0.f);
        }
    } else {
        const long nw = (long)D_OUT * D_IN / 8;   // 2,097,152
        const long nb = (long)D_OUT * RMOE / 8;   // 65,536
        long tid = (long)(blockIdx.x - 2048) * 256 + threadIdx.x;
        const float* src; u16* dst;
        if (tid < nw) {
            long e = tid * 8; long row = e >> 12; long col = e & 4095;
            src = bw + e; dst = Waug + row * KAUG + col;
        } else if (tid < nw + nb) {
            long e = (tid - nw) * 8; long row = e >> 7; long col = e & 127;
            src = lB + e; dst = Waug + row * KAUG + D_IN + col;
        } else {
            long e = (tid - nw - nb) * 8;
            src = lA + e; dst = A16 + e;
        }
        float4 a = ((const float4*)src)[0];
        float4 b = ((const float4*)src)[1];
        s16x8 o;
        o[0] = (short)f2bf(a.x); o[1] = (short)f2bf(a.y);
        o[2] = (short)f2bf(a.z); o[3] = (short)f2bf(a.w);
        o[4] = (short)f2bf(b.x); o[5] = (short)f2bf(b.y);
        o[6] = (short)f2bf(b.z); o[7] = (short)f2bf(b.w);
        *(s16x8*)dst = o;
    }
}

// ---------------------------------------------------------------------------
// Kernel 2 (validated R18): lora_h BM=64, BN=32, grid 512.
// ---------------------------------------------------------------------------
__global__ __launch_bounds__(256)
void lora_h_kernel(u16* __restrict__ Xaug, const u16* __restrict__ A16,
                   const float* __restrict__ gates) {
    __shared__ u16 sX[64 * 32];
    __shared__ u16 sW[32 * 32];
    int tid = threadIdx.x, wave = tid >> 6, lane = tid & 63;
    int bm = blockIdx.x >> 2, bn = blockIdx.x & 3;     // 128 x 4
    long m0 = (long)bm * 64; int n0 = bn * 32;
    int wr = wave >> 1, wc = wave & 1;
    int rowA = tid >> 2, oct = tid & 3;
    const u16* gx = Xaug + (m0 + rowA) * KAUG + oct * 8;
    const u16* gw = A16 + (long)(n0 + rowA) * D_IN + oct * 8;  // used only rowA<32
    u16* lx = sX + wave * 512;
    u16* lw = sW + wave * 512;   // only waves 0,1 stage B
    int cl = lane & 15, kh = lane >> 4;
    int aoff[2];
#pragma unroll
    for (int i = 0; i < 2; ++i)
        aoff[i] = (wr * 32 + i * 16 + cl) * 32 + kh * 8;
    int boff = (wc * 16 + cl) * 32 + kh * 8;
    f32x4 acc2[2];
    acc2[0] = (f32x4){0.f, 0.f, 0.f, 0.f};
    acc2[1] = (f32x4){0.f, 0.f, 0.f, 0.f};
    for (int kt = 0; kt < 128; ++kt) {
        __syncthreads();
        gload16(gx, lx);
        if (tid < 128) gload16(gw, lw);
        gx += 32; gw += 32;
        __syncthreads();
        s16x8 a[2], b;
        a[0] = *(const s16x8*)&sX[aoff[0]];
        a[1] = *(const s16x8*)&sX[aoff[1]];
        b = *(const s16x8*)&sW[boff];
#pragma unroll
        for (int mi = 0; mi < 2; ++mi)
            acc2[mi] = __builtin_amdgcn_mfma_f32_16x16x32_bf16(
                a[mi], b, acc2[mi], 0, 0, 0);
    }
    int col = n0 + wc * 16 + cl;     // rank 0..127
    int g = col >> 4;
#pragma unroll
    for (int mi = 0; mi < 2; ++mi) {
#pragma unroll
        for (int r = 0; r < 4; ++r) {
            long tok = m0 + wr * 32 + mi * 16 + kh * 4 + r;
            float v = acc2[mi][r] * gates[tok * 8 + g];
            Xaug[tok * KAUG + D_IN + col] = f2bf(v);
        }
    }
}

// ---------------------------------------------------------------------------
// Kernel 3 (validated R20): m201 8-phase template port. 256x256 tile, BK=64,
// 8 waves, 66 K-tiles = 33 iters of 2; counted vmcnt(4) at p3/p7 only.
// ---------------------------------------------------------------------------
__global__ __launch_bounds__(512, 2)
void main_gemm(const u16* __restrict__ Xaug, const u16* __restrict__ Waug,
               const float* __restrict__ bias, float* __restrict__ out) {
    __shared__ u16 lds[65536];     // 128 KiB
    const int tid = threadIdx.x;
    const int wave = tid >> 6, lane = tid & 63;
    const int cl = lane & 15, kh = lane >> 4;
    const int wr = wave >> 2, wc = wave & 3;

    // T1: bijective XCD swizzle (512 blocks, 512 % 8 == 0)
    int bid = blockIdx.x;
    int swz = (bid & 7) * 64 + (bid >> 3);
    long m0 = (long)(swz & 31) * 256;   // 32 M-blocks
    long n0 = (long)(swz >> 5) * 256;   // 16 N-blocks

    const int rbase = tid >> 3;
    const int sstg = ((tid & 7) ^ ((tid >> 3) & 7)) * 8;   // el offset
    const u16* gA = Xaug + (m0 + rbase) * KAUG + sstg;
    const u16* gB = Waug + (n0 + rbase) * KAUG + sstg;
    const int wst = (tid >> 6) * 512;   // wave-uniform LDS base (el)

    const int sk0 = ((kh) ^ (cl & 7)) * 8;
    const int sk1 = ((4 + kh) ^ (cl & 7)) * 8;
    const int ab0 = wr * 8192 + cl * 64;
    const int bb0 = 32768 + wc * 4096 + cl * 64;

    f32x4 acc[8][4];
#pragma unroll
    for (int m = 0; m < 8; ++m)
#pragma unroll
        for (int n = 0; n < 4; ++n) acc[m][n] = (f32x4){0.f, 0.f, 0.f, 0.f};

    s16x8 av[2][2], bv[4][2];

#define STAGE_A(kt, ht) do {                                                 \
        const u16* g_ = gA + ((long)(ht) * 128) * KAUG + (kt) * 64;          \
        u16* d_ = lds + ((kt) & 1) * 16384 + (ht) * 8192 + wst;              \
        gload16(g_, d_);                                                     \
        gload16(g_ + (long)64 * KAUG, d_ + 4096); } while (0)
#define STAGE_B(kt, ht) do {                                                 \
        const u16* g_ = gB + ((long)(ht) * 128) * KAUG + (kt) * 64;          \
        u16* d_ = lds + 32768 + ((kt) & 1) * 16384 + (ht) * 8192 + wst;      \
        gload16(g_, d_);                                                     \
        gload16(g_ + (long)64 * KAUG, d_ + 4096); } while (0)
#define RD_B(BUFO) do {                                                      \
        const u16* Lb_ = lds + (BUFO) + bb0;                                 \
        _Pragma("unroll")                                                    \
        for (int n_ = 0; n_ < 4; ++n_) {                                     \
            bv[n_][0] = *(const s16x8*)&Lb_[n_ * 1024 + sk0];                \
            bv[n_][1] = *(const s16x8*)&Lb_[n_ * 1024 + sk1]; } } while (0)
#define RD_A2(Q, BUFO) do {                                                  \
        const u16* La_ = lds + (BUFO) + ab0 + (Q) * 2048;                    \
        av[0][0] = *(const s16x8*)&La_[sk0];                                 \
        av[0][1] = *(const s16x8*)&La_[sk1];                                 \
        av[1][0] = *(const s16x8*)&La_[1024 + sk0];                          \
        av[1][1] = *(const s16x8*)&La_[1024 + sk1]; } while (0)
#define MF(Q) do { __builtin_amdgcn_s_setprio(1);                            \
        _Pragma("unroll")                                                    \
        for (int j_ = 0; j_ < 2; ++j_)                                       \
        _Pragma("unroll")                                                    \
        for (int n_ = 0; n_ < 4; ++n_)                                       \
        _Pragma("unroll")                                                    \
        for (int kk_ = 0; kk_ < 2; ++kk_)                                    \
            acc[2 * (Q) + j_][n_] = __builtin_amdgcn_mfma_f32_16x16x32_bf16( \
                av[j_][kk_], bv[n_][kk_], acc[2 * (Q) + j_][n_], 0, 0, 0);   \
        __builtin_amdgcn_s_setprio(0); } while (0)
#define BAR1_LG() do { __builtin_amdgcn_s_barrier();                         \
        asm volatile("s_waitcnt lgkmcnt(0)" ::: "memory");                   \
        __builtin_amdgcn_sched_barrier(0); } while (0)
#define BAR2() do { __builtin_amdgcn_s_barrier();                            \
        __builtin_amdgcn_sched_barrier(0); } while (0)

    STAGE_A(0, 0); STAGE_A(0, 1);
    STAGE_B(0, 0); STAGE_B(0, 1);
    STAGE_B(1, 0); STAGE_B(1, 1);
    asm volatile("s_waitcnt vmcnt(4)" ::: "memory");   // A(0),B(0) landed
    BAR2();

    for (int i = 0; i < 33; ++i) {
        const int k1 = 2 * i + 1, k2 = 2 * i + 2, k3 = 2 * i + 3;
        const bool ok = (i < 32);
        // ---- K-tile k0 (buf 0) ----
        RD_B(0); RD_A2(0, 0); STAGE_A(k1, 0);
        BAR1_LG(); MF(0); BAR2();
        RD_A2(1, 0); STAGE_A(k1, 1);
        BAR1_LG(); MF(1); BAR2();
        RD_A2(2, 0); if (ok) STAGE_B(k2, 0);
        BAR1_LG(); MF(2); BAR2();
        RD_A2(3, 0); if (ok) STAGE_B(k2, 1);
        BAR1_LG(); MF(3);
        if (ok) asm volatile("s_waitcnt vmcnt(4)" ::: "memory");
        else    asm volatile("s_waitcnt vmcnt(0)" ::: "memory");
        BAR2();
        // ---- K-tile k1 (buf 1) ----
        RD_B(16384); RD_A2(0, 16384); if (ok) STAGE_A(k2, 0);
        BAR1_LG(); MF(0); BAR2();
        RD_A2(1, 16384); if (ok) STAGE_A(k2, 1);
        BAR1_LG(); MF(1); BAR2();
        RD_A2(2, 16384); if (ok) STAGE_B(k3, 0);
        BAR1_LG(); MF(2); BAR2();
        RD_A2(3, 16384); if (ok) STAGE_B(k3, 1);
        BAR1_LG(); MF(3);
        if (ok) asm volatile("s_waitcnt vmcnt(4)" ::: "memory");
        BAR2();
    }
#undef STAGE_A
#undef STAGE_B
#undef RD_B
#undef RD_A2
#undef MF
#undef BAR1_LG
#undef BAR2

#pragma unroll
    for (int n = 0; n < 4; ++n) {
        long col = n0 + wc * 64 + n * 16 + cl;
        float bvv = bias[col];
#pragma unroll
        for (int m = 0; m < 8; ++m) {
            long row = m0 + wr * 128 + m * 16 + kh * 4;
#pragma unroll
            for (int r = 0; r < 4; ++r)
                out[(row + r) * (long)D_OUT + col] = acc[m][n][r] + bvv;
        }
    }
}

// ---------------------------------------------------------------------------
extern "C" void kernel_launch(void* const* d_in, const int* in_sizes, int n_in,
                              void* d_out, int out_size, void* d_ws, size_t ws_size,
                              hipStream_t stream) {
    const float* x  = (const float*)d_in[0];
    const float* bw = (const float*)d_in[1];
    const float* bb = (const float*)d_in[2];
    const float* lA = (const float*)d_in[3];
    const float* lB = (const float*)d_in[4];
    const float* rw = (const float*)d_in[5];
    const float* sc = (const float*)d_in[6];
    float* out = (float*)d_out;

    char* ws = (char*)d_ws;
    u16* Xaug  = (u16*)ws;                      // 8192*4224*2 = 69,206,016 B
    u16* Waug  = (u16*)(ws + 69206016);         // 4096*4224*2 = 34,603,008 B
    u16* A16   = (u16*)(ws + 103809024);        // 128*4096*2  =  1,048,576 B
    float* gates = (float*)(ws + 104857600);    // 8192*8*4    =    262,144 B

    prep_kernel<<<10752, 256, 0, stream>>>(x, rw, sc, bw, lA, lB,
                                           Xaug, Waug, A16, gates);
    lora_h_kernel<<<512, 256, 0, stream>>>(Xaug, A16, gates);
    main_gemm<<<512, 512, 0, stream>>>(Xaug, Waug, bb, out);
}

// Round 22
// 356.390 us; speedup vs baseline: 1.1740x; 1.0190x over previous
//
#include <hip/hip_runtime.h>
#include <cstdint>

typedef unsigned short u16;
typedef float  f32x4 __attribute__((ext_vector_type(4)));
typedef short  s16x4 __attribute__((ext_vector_type(4)));
typedef short  s16x8 __attribute__((ext_vector_type(8)));

#define D_IN  4096
#define D_OUT 4096
#define RMOE  128
#define KAUG  4224   /* D_IN + RMOE = 66 * 64 */
#define NTOK  8192   /* B*S = 4*2048 */

__device__ __forceinline__ u16 f2bf(float f) {
    unsigned u = __builtin_bit_cast(unsigned, f);
    unsigned r = u + 0x7fffu + ((u >> 16) & 1u);   // RNE
    return (u16)(r >> 16);
}

__device__ __forceinline__ void gload16(const void* g, void* l) {
    __builtin_amdgcn_global_load_lds(
        (const __attribute__((address_space(1))) void*)g,
        (__attribute__((address_space(3))) void*)l, 16, 0, 0);
}

// ---------------------------------------------------------------------------
// Kernel 1 (ROUND-22): fused prep. Router blocks now PREFETCH-1 the x row
// float4 (issue x[i+1] right after barrier i, consume next iter) — breaks
// the 16x serial load-use latency chain; values and accumulation order
// bit-identical to the validated router. rw LDS-shared across the block's
// 4 waves (validated R21). Blocks 2048..10751: conversions (validated R10).
// ---------------------------------------------------------------------------
__global__ __launch_bounds__(256)
void prep_kernel(const float* __restrict__ x, const float* __restrict__ rw,
                 const float* __restrict__ scal, const float* __restrict__ bw,
                 const float* __restrict__ lA, const float* __restrict__ lB,
                 u16* __restrict__ Xaug, u16* __restrict__ Waug,
                 u16* __restrict__ A16, float* __restrict__ gates) {
    __shared__ u16 srw[2][4096];   // 2 x 8KB: [e 0..7][lane 0..63] float4
    if (blockIdx.x < 2048) {
        int wave = threadIdx.x >> 6, lane = threadIdx.x & 63;
        int t = blockIdx.x * 4 + wave;
        const float4* xp = (const float4*)(x + (long)t * D_IN);
        u16* xa = Xaug + (long)t * KAUG;
        float acc[8];
#pragma unroll
        for (int e = 0; e < 8; ++e) acc[e] = 0.f;

        // stage chunk 0: wave w loads expert rows w and w+4
        gload16(rw + wave * 4096 + lane * 4, &srw[0][wave * 512]);
        gload16(rw + (4 + wave) * 4096 + lane * 4, &srw[0][2048 + wave * 512]);

        float4 xv = xp[lane];          // prefetch i=0
        for (int i = 0; i < 16; ++i) {
            __syncthreads();   // stage(i) + x(i) landed (vmcnt0), use(i-1) done
            if (i < 15) {
                const float* s = rw + i * 256 + 256;   // chunk i+1
                gload16(s + wave * 4096 + lane * 4,
                        &srw[(i + 1) & 1][wave * 512]);
                gload16(s + (4 + wave) * 4096 + lane * 4,
                        &srw[(i + 1) & 1][2048 + wave * 512]);
            }
            float4 xnext;
            if (i < 15) xnext = xp[(i + 1) * 64 + lane];   // prefetch-1
            s16x4 o;
            o[0] = (short)f2bf(xv.x); o[1] = (short)f2bf(xv.y);
            o[2] = (short)f2bf(xv.z); o[3] = (short)f2bf(xv.w);
            *(s16x4*)(xa + (i * 64 + lane) * 4) = o;
            const float4* wvp = (const float4*)srw[i & 1];
#pragma unroll
            for (int e = 0; e < 8; ++e) {
                float4 wv = wvp[e * 64 + lane];
                acc[e] += xv.x * wv.x + xv.y * wv.y + xv.z * wv.z + xv.w * wv.w;
            }
            if (i < 15) xv = xnext;
        }
#pragma unroll
        for (int e = 0; e < 8; ++e) {
#pragma unroll
            for (int off = 32; off > 0; off >>= 1)
                acc[e] += __shfl_xor(acc[e], off, 64);
        }
        if (lane == 0) {
            int i1 = 0; float v1 = acc[0];
#pragma unroll
            for (int e = 1; e < 8; ++e) if (acc[e] > v1) { v1 = acc[e]; i1 = e; }
            int i2 = -1; float v2 = -3.4e38f;
#pragma unroll
            for (int e = 0; e < 8; ++e) if (e != i1 && acc[e] > v2) { v2 = acc[e]; i2 = e; }
            float g1 = 1.f / (1.f + expf(v2 - v1));
            float g2 = 1.f - g1;
            float* gp = gates + (long)t * 8;
#pragma unroll
            for (int e = 0; e < 8; ++e)
                gp[e] = (e == i1) ? g1 * scal[e] : ((e == i2) ? g2 * scal[e] : 0.f);
        }
    } else {
        const long nw = (long)D_OUT * D_IN / 8;   // 2,097,152
        const long nb = (long)D_OUT * RMOE / 8;   // 65,536
        long tid = (long)(blockIdx.x - 2048) * 256 + threadIdx.x;
        const float* src; u16* dst;
        if (tid < nw) {
            long e = tid * 8; long row = e >> 12; long col = e & 4095;
            src = bw + e; dst = Waug + row * KAUG + col;
        } else if (tid < nw + nb) {
            long e = (tid - nw) * 8; long row = e >> 7; long col = e & 127;
            src = lB + e; dst = Waug + row * KAUG + D_IN + col;
        } else {
            long e = (tid - nw - nb) * 8;
            src = lA + e; dst = A16 + e;
        }
        float4 a = ((const float4*)src)[0];
        float4 b = ((const float4*)src)[1];
        s16x8 o;
        o[0] = (short)f2bf(a.x); o[1] = (short)f2bf(a.y);
        o[2] = (short)f2bf(a.z); o[3] = (short)f2bf(a.w);
        o[4] = (short)f2bf(b.x); o[5] = (short)f2bf(b.y);
        o[6] = (short)f2bf(b.z); o[7] = (short)f2bf(b.w);
        *(s16x8*)dst = o;
    }
}

// ---------------------------------------------------------------------------
// Kernel 2 (validated R18): lora_h BM=64, BN=32, grid 512.
// ---------------------------------------------------------------------------
__global__ __launch_bounds__(256)
void lora_h_kernel(u16* __restrict__ Xaug, const u16* __restrict__ A16,
                   const float* __restrict__ gates) {
    __shared__ u16 sX[64 * 32];
    __shared__ u16 sW[32 * 32];
    int tid = threadIdx.x, wave = tid >> 6, lane = tid & 63;
    int bm = blockIdx.x >> 2, bn = blockIdx.x & 3;     // 128 x 4
    long m0 = (long)bm * 64; int n0 = bn * 32;
    int wr = wave >> 1, wc = wave & 1;
    int rowA = tid >> 2, oct = tid & 3;
    const u16* gx = Xaug + (m0 + rowA) * KAUG + oct * 8;
    const u16* gw = A16 + (long)(n0 + rowA) * D_IN + oct * 8;  // used only rowA<32
    u16* lx = sX + wave * 512;
    u16* lw = sW + wave * 512;   // only waves 0,1 stage B
    int cl = lane & 15, kh = lane >> 4;
    int aoff[2];
#pragma unroll
    for (int i = 0; i < 2; ++i)
        aoff[i] = (wr * 32 + i * 16 + cl) * 32 + kh * 8;
    int boff = (wc * 16 + cl) * 32 + kh * 8;
    f32x4 acc2[2];
    acc2[0] = (f32x4){0.f, 0.f, 0.f, 0.f};
    acc2[1] = (f32x4){0.f, 0.f, 0.f, 0.f};
    for (int kt = 0; kt < 128; ++kt) {
        __syncthreads();
        gload16(gx, lx);
        if (tid < 128) gload16(gw, lw);
        gx += 32; gw += 32;
        __syncthreads();
        s16x8 a[2], b;
        a[0] = *(const s16x8*)&sX[aoff[0]];
        a[1] = *(const s16x8*)&sX[aoff[1]];
        b = *(const s16x8*)&sW[boff];
#pragma unroll
        for (int mi = 0; mi < 2; ++mi)
            acc2[mi] = __builtin_amdgcn_mfma_f32_16x16x32_bf16(
                a[mi], b, acc2[mi], 0, 0, 0);
    }
    int col = n0 + wc * 16 + cl;     // rank 0..127
    int g = col >> 4;
#pragma unroll
    for (int mi = 0; mi < 2; ++mi) {
#pragma unroll
        for (int r = 0; r < 4; ++r) {
            long tok = m0 + wr * 32 + mi * 16 + kh * 4 + r;
            float v = acc2[mi][r] * gates[tok * 8 + g];
            Xaug[tok * KAUG + D_IN + col] = f2bf(v);
        }
    }
}

// ---------------------------------------------------------------------------
// Kernel 3 (validated R20): m201 8-phase template port. 256x256 tile, BK=64,
// 8 waves, 66 K-tiles = 33 iters of 2; counted vmcnt(4) at p3/p7 only.
// ---------------------------------------------------------------------------
__global__ __launch_bounds__(512, 2)
void main_gemm(const u16* __restrict__ Xaug, const u16* __restrict__ Waug,
               const float* __restrict__ bias, float* __restrict__ out) {
    __shared__ u16 lds[65536];     // 128 KiB
    const int tid = threadIdx.x;
    const int wave = tid >> 6, lane = tid & 63;
    const int cl = lane & 15, kh = lane >> 4;
    const int wr = wave >> 2, wc = wave & 3;

    // T1: bijective XCD swizzle (512 blocks, 512 % 8 == 0)
    int bid = blockIdx.x;
    int swz = (bid & 7) * 64 + (bid >> 3);
    long m0 = (long)(swz & 31) * 256;   // 32 M-blocks
    long n0 = (long)(swz >> 5) * 256;   // 16 N-blocks

    const int rbase = tid >> 3;
    const int sstg = ((tid & 7) ^ ((tid >> 3) & 7)) * 8;   // el offset
    const u16* gA = Xaug + (m0 + rbase) * KAUG + sstg;
    const u16* gB = Waug + (n0 + rbase) * KAUG + sstg;
    const int wst = (tid >> 6) * 512;   // wave-uniform LDS base (el)

    const int sk0 = ((kh) ^ (cl & 7)) * 8;
    const int sk1 = ((4 + kh) ^ (cl & 7)) * 8;
    const int ab0 = wr * 8192 + cl * 64;
    const int bb0 = 32768 + wc * 4096 + cl * 64;

    f32x4 acc[8][4];
#pragma unroll
    for (int m = 0; m < 8; ++m)
#pragma unroll
        for (int n = 0; n < 4; ++n) acc[m][n] = (f32x4){0.f, 0.f, 0.f, 0.f};

    s16x8 av[2][2], bv[4][2];

#define STAGE_A(kt, ht) do {                                                 \
        const u16* g_ = gA + ((long)(ht) * 128) * KAUG + (kt) * 64;          \
        u16* d_ = lds + ((kt) & 1) * 16384 + (ht) * 8192 + wst;              \
        gload16(g_, d_);                                                     \
        gload16(g_ + (long)64 * KAUG, d_ + 4096); } while (0)
#define STAGE_B(kt, ht) do {                                                 \
        const u16* g_ = gB + ((long)(ht) * 128) * KAUG + (kt) * 64;          \
        u16* d_ = lds + 32768 + ((kt) & 1) * 16384 + (ht) * 8192 + wst;      \
        gload16(g_, d_);                                                     \
        gload16(g_ + (long)64 * KAUG, d_ + 4096); } while (0)
#define RD_B(BUFO) do {                                                      \
        const u16* Lb_ = lds + (BUFO) + bb0;                                 \
        _Pragma("unroll")                                                    \
        for (int n_ = 0; n_ < 4; ++n_) {                                     \
            bv[n_][0] = *(const s16x8*)&Lb_[n_ * 1024 + sk0];                \
            bv[n_][1] = *(const s16x8*)&Lb_[n_ * 1024 + sk1]; } } while (0)
#define RD_A2(Q, BUFO) do {                                                  \
        const u16* La_ = lds + (BUFO) + ab0 + (Q) * 2048;                    \
        av[0][0] = *(const s16x8*)&La_[sk0];                                 \
        av[0][1] = *(const s16x8*)&La_[sk1];                                 \
        av[1][0] = *(const s16x8*)&La_[1024 + sk0];                          \
        av[1][1] = *(const s16x8*)&La_[1024 + sk1]; } while (0)
#define MF(Q) do { __builtin_amdgcn_s_setprio(1);                            \
        _Pragma("unroll")                                                    \
        for (int j_ = 0; j_ < 2; ++j_)                                       \
        _Pragma("unroll")                                                    \
        for (int n_ = 0; n_ < 4; ++n_)                                       \
        _Pragma("unroll")                                                    \
        for (int kk_ = 0; kk_ < 2; ++kk_)                                    \
            acc[2 * (Q) + j_][n_] = __builtin_amdgcn_mfma_f32_16x16x32_bf16( \
                av[j_][kk_], bv[n_][kk_], acc[2 * (Q) + j_][n_], 0, 0, 0);   \
        __builtin_amdgcn_s_setprio(0); } while (0)
#define BAR1_LG() do { __builtin_amdgcn_s_barrier();                         \
        asm volatile("s_waitcnt lgkmcnt(0)" ::: "memory");                   \
        __builtin_amdgcn_sched_barrier(0); } while (0)
#define BAR2() do { __builtin_amdgcn_s_barrier();                            \
        __builtin_amdgcn_sched_barrier(0); } while (0)

    STAGE_A(0, 0); STAGE_A(0, 1);
    STAGE_B(0, 0); STAGE_B(0, 1);
    STAGE_B(1, 0); STAGE_B(1, 1);
    asm volatile("s_waitcnt vmcnt(4)" ::: "memory");   // A(0),B(0) landed
    BAR2();

    for (int i = 0; i < 33; ++i) {
        const int k1 = 2 * i + 1, k2 = 2 * i + 2, k3 = 2 * i + 3;
        const bool ok = (i < 32);
        // ---- K-tile k0 (buf 0) ----
        RD_B(0); RD_A2(0, 0); STAGE_A(k1, 0);
        BAR1_LG(); MF(0); BAR2();
        RD_A2(1, 0); STAGE_A(k1, 1);
        BAR1_LG(); MF(1); BAR2();
        RD_A2(2, 0); if (ok) STAGE_B(k2, 0);
        BAR1_LG(); MF(2); BAR2();
        RD_A2(3, 0); if (ok) STAGE_B(k2, 1);
        BAR1_LG(); MF(3);
        if (ok) asm volatile("s_waitcnt vmcnt(4)" ::: "memory");
        else    asm volatile("s_waitcnt vmcnt(0)" ::: "memory");
        BAR2();
        // ---- K-tile k1 (buf 1) ----
        RD_B(16384); RD_A2(0, 16384); if (ok) STAGE_A(k2, 0);
        BAR1_LG(); MF(0); BAR2();
        RD_A2(1, 16384); if (ok) STAGE_A(k2, 1);
        BAR1_LG(); MF(1); BAR2();
        RD_A2(2, 16384); if (ok) STAGE_B(k3, 0);
        BAR1_LG(); MF(2); BAR2();
        RD_A2(3, 16384); if (ok) STAGE_B(k3, 1);
        BAR1_LG(); MF(3);
        if (ok) asm volatile("s_waitcnt vmcnt(4)" ::: "memory");
        BAR2();
    }
#undef STAGE_A
#undef STAGE_B
#undef RD_B
#undef RD_A2
#undef MF
#undef BAR1_LG
#undef BAR2

#pragma unroll
    for (int n = 0; n < 4; ++n) {
        long col = n0 + wc * 64 + n * 16 + cl;
        float bvv = bias[col];
#pragma unroll
        for (int m = 0; m < 8; ++m) {
            long row = m0 + wr * 128 + m * 16 + kh * 4;
#pragma unroll
            for (int r = 0; r < 4; ++r)
                out[(row + r) * (long)D_OUT + col] = acc[m][n][r] + bvv;
        }
    }
}

// ---------------------------------------------------------------------------
extern "C" void kernel_launch(void* const* d_in, const int* in_sizes, int n_in,
                              void* d_out, int out_size, void* d_ws, size_t ws_size,
                              hipStream_t stream) {
    const float* x  = (const float*)d_in[0];
    const float* bw = (const float*)d_in[1];
    const float* bb = (const float*)d_in[2];
    const float* lA = (const float*)d_in[3];
    const float* lB = (const float*)d_in[4];
    const float* rw = (const float*)d_in[5];
    const float* sc = (const float*)d_in[6];
    float* out = (float*)d_out;

    char* ws = (char*)d_ws;
    u16* Xaug  = (u16*)ws;                      // 8192*4224*2 = 69,206,016 B
    u16* Waug  = (u16*)(ws + 69206016);         // 4096*4224*2 = 34,603,008 B
    u16* A16   = (u16*)(ws + 103809024);        // 128*4096*2  =  1,048,576 B
    float* gates = (float*)(ws + 104857600);    // 8192*8*4    =    262,144 B

    prep_kernel<<<10752, 256, 0, stream>>>(x, rw, sc, bw, lA, lB,
                                           Xaug, Waug, A16, gates);
    lora_h_kernel<<<512, 256, 0, stream>>>(Xaug, A16, gates);
    main_gemm<<<512, 512, 0, stream>>>(Xaug, Waug, bb, out);
}